// Round 1
// baseline (461.794 us; speedup 1.0000x reference)
//
#include <hip/hip_runtime.h>
#include <hip/hip_bf16.h>

// kNNFit: out[b] = beta * (mean_m F(1 - WHD[m,b]/||W||_1) * Y[m] + alpha)
// WHD[m,b] = s1[b] + sum_d X2[d,m] * (+-W[d]),  sign = (1 - 2*X1[d,b])
// GEMM C[M,64] = X2^T @ Bm via bf16 MFMA (X2 bits and +-bf16(W) are exact bf16).

#define DD 512
#define MM 131072
#define BQ 64
#define MWG 128
#define NWG (MM / MWG) // 1024

typedef __attribute__((ext_vector_type(8))) short short8;  // 8 bf16 (4 VGPRs)
typedef __attribute__((ext_vector_type(4))) float floatx4; // 4 fp32 acc

__global__ __launch_bounds__(256, 2) void knn_main(
    const int* __restrict__ X1, const int* __restrict__ X2,
    const float* __restrict__ Y, const float* __restrict__ W,
    const float* __restrict__ kp, const float* __restrict__ jp,
    float* __restrict__ partials) {
  // LDS: A tile [128 m][pitch 80B: 4 kb-octets * 16B + 16B pad] + Y cache
  __shared__ __align__(16) unsigned char smem[MWG * 80 + MWG * 4];
  float* Ys = (float*)(smem + MWG * 80);

  const int tid = threadIdx.x;
  const int w = tid >> 6;   // wave id 0..3 (owns b-tile w, d-octet w in staging)
  const int l = tid & 63;   // lane
  const int col = l & 15;   // MFMA 16-dim index
  const int quad = l >> 4;  // MFMA k-group / row-group
  const int m0 = blockIdx.x * MWG;
  const int b = w * 16 + col;

  if (tid < MWG) Ys[tid] = Y[m0 + tid];

  // ---- prologue: build B fragments (+-bf16(W)) and s1[b], norm ----
  float s1p = 0.f;
  short8 bfrag[16];
#pragma unroll
  for (int ks = 0; ks < 16; ++ks) {
    const int dbase = ks * 32 + quad * 8;
    short8 f;
#pragma unroll
    for (int j = 0; j < 8; ++j) {
      const int d = dbase + j;
      const float wd = W[d];
      const int x1 = X1[d * BQ + b];           // 4 cache lines / wave: cheap, L2-hot
      s1p += wd * (float)x1;
      __hip_bfloat16 h = __float2bfloat16(wd);
      unsigned short hb = __builtin_bit_cast(unsigned short, h);
      f[j] = (short)(x1 ? (unsigned short)(hb ^ 0x8000u) : hb);
    }
    bfrag[ks] = f;
  }
  // s1[b] = sum over all 512 d: sum the 4 quad-partials
  s1p += __shfl_xor(s1p, 16);
  s1p += __shfl_xor(s1p, 32);
  const float s1b = s1p;

  float nw = 0.f;
  const float4* W4 = (const float4*)W;
#pragma unroll 8
  for (int i = 0; i < DD / 4; ++i) {
    float4 wv = W4[i];
    nw += fabsf(wv.x) + fabsf(wv.y) + fabsf(wv.z) + fabsf(wv.w);
  }
  const float inv_norm = 1.0f / (nw + 1e-6f);
  const float kk = kp[0], jj = jp[0];

  floatx4 acc[8];
#pragma unroll
  for (int mt = 0; mt < 8; ++mt) acc[mt] = (floatx4){0.f, 0.f, 0.f, 0.f};

  // ---- K loop: 16 steps of 32 d's ----
#pragma unroll
  for (int ks = 0; ks < 16; ++ks) {
    // wave w loads rows d = ks*32 + w*8 + r (r=0..7), 2 m's per lane (coalesced 512B/row)
    const int* gbase = X2 + (size_t)(ks * 32 + w * 8) * MM + m0 + 2 * l;
    int2 v[8];
#pragma unroll
    for (int r = 0; r < 8; ++r) v[r] = *(const int2*)(gbase + (size_t)r * MM);
    // transpose + 0/1 -> bf16 pack: (a | b<<16) * 0x3F80
    unsigned int u0[4], u1[4];
#pragma unroll
    for (int q = 0; q < 4; ++q) {
      u0[q] = (unsigned int)(v[2 * q].x | (v[2 * q + 1].x << 16)) * 0x3F80u;
      u1[q] = (unsigned int)(v[2 * q].y | (v[2 * q + 1].y << 16)) * 0x3F80u;
    }
    __syncthreads(); // prior iteration's ds_reads done
    *(uint4*)(smem + (size_t)(2 * l + 0) * 80 + w * 16) = make_uint4(u0[0], u0[1], u0[2], u0[3]);
    *(uint4*)(smem + (size_t)(2 * l + 1) * 80 + w * 16) = make_uint4(u1[0], u1[1], u1[2], u1[3]);
    __syncthreads();
#pragma unroll
    for (int mt = 0; mt < 8; ++mt) {
      short8 af = *(const short8*)(smem + (size_t)(mt * 16 + col) * 80 + quad * 16);
      acc[mt] = __builtin_amdgcn_mfma_f32_16x16x32_bf16(af, bfrag[ks], acc[mt], 0, 0, 0);
    }
  }

  // ---- epilogue: squash F, weight by Y, reduce over m ----
  const float c1 = 1.0f - kk;
  const float c2 = 1.0f + jj;
  float psum = 0.f;
#pragma unroll
  for (int mt = 0; mt < 8; ++mt) {
#pragma unroll
    for (int i = 0; i < 4; ++i) {
      const float whd = s1b + acc[mt][i];
      const float x = 1.0f - whd * inv_norm;
      const float ax = fabsf(x);
      const float inner = x * c1 / (kk * (1.0f - 2.0f * ax) + 1.0f);
      const float t2 = 2.0f * inner - 1.0f;
      const float at = fabsf(t2);
      const float fq = 0.5f + 0.5f * t2 * c2 / (-jj * (1.0f - 2.0f * at) + 1.0f);
      psum += fq * Ys[mt * 16 + quad * 4 + i];
    }
  }
  // rows are spread across lane-quads; sum them so lanes 0..15 of each wave hold b-partials
  psum += __shfl_xor(psum, 16);
  psum += __shfl_xor(psum, 32);
  if (l < 16) partials[(size_t)blockIdx.x * 64 + b] = psum;
}

__global__ __launch_bounds__(256) void knn_finalize(
    const float* __restrict__ partials, const float* __restrict__ alphap,
    const float* __restrict__ betap, float* __restrict__ out) {
  __shared__ float red[256];
  const int t = threadIdx.x;
  const int b = t & 63, g = t >> 6;
  float s = 0.f;
  for (int i = g; i < NWG; i += 4) s += partials[(size_t)i * 64 + b];
  red[t] = s;
  __syncthreads();
  if (t < 64) {
    const float tot = red[t] + red[t + 64] + red[t + 128] + red[t + 192];
    const float score = tot * (1.0f / (float)MM);
    out[t] = betap[0] * (score + alphap[0]);
  }
}

extern "C" void kernel_launch(void* const* d_in, const int* in_sizes, int n_in,
                              void* d_out, int out_size, void* d_ws, size_t ws_size,
                              hipStream_t stream) {
  const int* X1 = (const int*)d_in[0];        // [512, 64] int32 bits
  const int* X2 = (const int*)d_in[1];        // [512, 131072] int32 bits
  const float* Y = (const float*)d_in[3];     // [131072]
  const float* W = (const float*)d_in[4];     // [512]
  const float* alphap = (const float*)d_in[5];
  const float* betap = (const float*)d_in[6];
  const float* kp = (const float*)d_in[7];
  const float* jp = (const float*)d_in[8];

  float* partials = (float*)d_ws; // NWG*64*4 = 256 KB scratch

  knn_main<<<NWG, 256, 0, stream>>>(X1, X2, Y, W, kp, jp, partials);
  knn_finalize<<<1, 256, 0, stream>>>(partials, alphap, betap, (float*)d_out);
}

// Round 2
// 397.670 us; speedup vs baseline: 1.1612x; 1.1612x over previous
//
#include <hip/hip_runtime.h>
#include <hip/hip_bf16.h>

// kNNFit: out[b] = beta * (mean_m F(1 - WHD[m,b]/||W||_1) * Y[m] + alpha)
// WHD[m,b] = s1[b] + sum_d X2[d,m] * (+-W[d]),  sign = (1 - 2*X1[d,b])
// GEMM C[M,64] = X2^T @ (+-W) via bf16 MFMA; X2 bits and +-bf16(W) are exact bf16.
//
// Structure: setup kernel precomputes per-wave B-fragments (+-bf16 W), s1, 1/||W||
// into ws; main kernel is a pure HBM stream over X2 (268 MB) with 1-deep explicit
// prefetch; finalize reduces 2048 partials per b.

#define DD 512
#define MM 131072
#define BQ 64
#define MWG 64
#define NWG (MM / MWG)          // 2048 blocks
#define WS_BFRAG 0              // 64 KB: short8[4][16][64]  ((w*16+ks)*64+l)
#define WS_META  65536          // float[65]: s1[64], inv_norm
#define WS_PART  131072         // float[64][NWG] partials (b-major for coalesced finalize)

typedef __attribute__((ext_vector_type(8))) short short8;  // 8 bf16 (4 VGPRs)
typedef __attribute__((ext_vector_type(4))) float floatx4; // 4 fp32 acc

__global__ __launch_bounds__(256) void knn_setup(
    const int* __restrict__ X1, const float* __restrict__ W,
    void* __restrict__ ws) {
  short8* bm = (short8*)((char*)ws + WS_BFRAG);
  float* meta = (float*)((char*)ws + WS_META);
  const int tid = threadIdx.x;
#pragma unroll
  for (int i = 0; i < 16; ++i) {
    const int e = tid + 256 * i;           // e = (w*16+ks)*64 + l
    const int l = e & 63, ks = (e >> 6) & 15, w = e >> 10;
    const int col = l & 15, quad = l >> 4;
    const int b = w * 16 + col;
    short8 f;
#pragma unroll
    for (int j = 0; j < 8; ++j) {
      const int d = ks * 32 + quad * 8 + j;
      unsigned short hb = __builtin_bit_cast(unsigned short, __float2bfloat16(W[d]));
      if (X1[d * BQ + b]) hb ^= 0x8000u;   // sign flip where query bit = 1
      f[j] = (short)hb;
    }
    bm[e] = f;
  }
  if (tid < BQ) {                          // s1[b] = sum_d W[d]*X1[d,b]
    float s = 0.f;
    for (int d = 0; d < DD; ++d) s += W[d] * (float)X1[d * BQ + tid];
    meta[tid] = s;
  }
  if (tid == 64) {                         // 1/(||W||_1 + eps)
    float nw = 0.f;
    for (int d = 0; d < DD; ++d) nw += fabsf(W[d]);
    meta[64] = 1.0f / (nw + 1e-6f);
  }
}

__global__ __launch_bounds__(256, 4) void knn_main(
    const int* __restrict__ X2, const float* __restrict__ Y,
    const float* __restrict__ kp, const float* __restrict__ jp,
    const void* __restrict__ ws_ro, float* __restrict__ partials) {
  // LDS: bf16 A-tile [64 m][32 d] pitch 64B + Y cache
  __shared__ __align__(16) unsigned char smem[MWG * 64 + MWG * 4];
  float* Ys = (float*)(smem + MWG * 64);
  const short8* bm = (const short8*)((const char*)ws_ro + WS_BFRAG);
  const float* meta = (const float*)((const char*)ws_ro + WS_META);

  const int tid = threadIdx.x;
  const int w = tid >> 6, l = tid & 63;
  const int col = l & 15, quad = l >> 4;
  const int m0 = blockIdx.x * MWG;

  if (tid < MWG) Ys[tid] = Y[m0 + tid];

  const float s1b = meta[w * 16 + col];
  const float inv_norm = meta[64];
  const float kk = kp[0], jj = jp[0];

  floatx4 acc[4];
#pragma unroll
  for (int mt = 0; mt < 4; ++mt) acc[mt] = (floatx4){0.f, 0.f, 0.f, 0.f};

  // wave w stages rows d = ks*32 + w*8 + r; lane l covers m = m0 + l (256B coalesced/row)
  const int* g0 = X2 + (size_t)(w * 8) * MM + m0 + l;
  int v[8], vn[8];
#pragma unroll
  for (int r = 0; r < 8; ++r) v[r] = g0[(size_t)r * MM];
  short8 bf = bm[(w * 16 + 0) * 64 + l];

#pragma unroll
  for (int ks = 0; ks < 16; ++ks) {
    short8 bfn = bf;
    if (ks < 15) {  // prefetch next step's loads before this step's pack/barriers
      const int* g = g0 + (size_t)((ks + 1) * 32) * MM;
#pragma unroll
      for (int r = 0; r < 8; ++r) vn[r] = g[(size_t)r * MM];
      bfn = bm[(w * 16 + ks + 1) * 64 + l];
    }
    // 0/1 int pairs -> packed bf16 pair: (a | b<<16) * 0x3F80
    unsigned int u[4];
#pragma unroll
    for (int q = 0; q < 4; ++q)
      u[q] = (unsigned int)(v[2 * q] | (v[2 * q + 1] << 16)) * 0x3F80u;
    __syncthreads();
    *(uint4*)(smem + (size_t)l * 64 + w * 16) = make_uint4(u[0], u[1], u[2], u[3]);
    __syncthreads();
#pragma unroll
    for (int mt = 0; mt < 4; ++mt) {
      short8 af = *(const short8*)(smem + (size_t)(mt * 16 + col) * 64 + quad * 16);
      acc[mt] = __builtin_amdgcn_mfma_f32_16x16x32_bf16(af, bf, acc[mt], 0, 0, 0);
    }
#pragma unroll
    for (int r = 0; r < 8; ++r) v[r] = vn[r];
    bf = bfn;
  }

  // epilogue: rational squash F, weight by Y, reduce over this block's 64 m's
  const float c1 = 1.0f - kk;
  const float c2 = 1.0f + jj;
  float psum = 0.f;
#pragma unroll
  for (int mt = 0; mt < 4; ++mt) {
#pragma unroll
    for (int i = 0; i < 4; ++i) {
      const float whd = s1b + acc[mt][i];
      const float x = 1.0f - whd * inv_norm;
      const float ax = fabsf(x);
      const float inner = x * c1 / (kk * (1.0f - 2.0f * ax) + 1.0f);
      const float t2 = 2.0f * inner - 1.0f;
      const float at = fabsf(t2);
      const float fq = 0.5f + 0.5f * t2 * c2 / (-jj * (1.0f - 2.0f * at) + 1.0f);
      psum += fq * Ys[mt * 16 + quad * 4 + i];   // C/D row = quad*4 + i
    }
  }
  psum += __shfl_xor(psum, 16);
  psum += __shfl_xor(psum, 32);
  if (l < 16) partials[(size_t)(w * 16 + col) * NWG + blockIdx.x] = psum;
}

__global__ __launch_bounds__(256) void knn_finalize(
    const float* __restrict__ partials, const float* __restrict__ alphap,
    const float* __restrict__ betap, float* __restrict__ out) {
  __shared__ float red[256];
  const int b = blockIdx.x, t = threadIdx.x;
  float s = 0.f;
#pragma unroll
  for (int i = 0; i < NWG / 256; ++i) s += partials[(size_t)b * NWG + i * 256 + t];
  red[t] = s;
  __syncthreads();
  if (t < 64) {
    float x = red[t] + red[t + 64] + red[t + 128] + red[t + 192];
    x += __shfl_xor(x, 32);
    x += __shfl_xor(x, 16);
    x += __shfl_xor(x, 8);
    x += __shfl_xor(x, 4);
    x += __shfl_xor(x, 2);
    x += __shfl_xor(x, 1);
    if (t == 0) out[b] = betap[0] * (x * (1.0f / (float)MM) + alphap[0]);
  }
}

extern "C" void kernel_launch(void* const* d_in, const int* in_sizes, int n_in,
                              void* d_out, int out_size, void* d_ws, size_t ws_size,
                              hipStream_t stream) {
  const int* X1 = (const int*)d_in[0];     // [512, 64] int32 bits
  const int* X2 = (const int*)d_in[1];     // [512, 131072] int32 bits
  const float* Y = (const float*)d_in[3];  // [131072]
  const float* W = (const float*)d_in[4];  // [512]
  const float* alphap = (const float*)d_in[5];
  const float* betap = (const float*)d_in[6];
  const float* kp = (const float*)d_in[7];
  const float* jp = (const float*)d_in[8];

  float* partials = (float*)((char*)d_ws + WS_PART);

  knn_setup<<<1, 256, 0, stream>>>(X1, W, d_ws);
  knn_main<<<NWG, 256, 0, stream>>>(X2, Y, kp, jp, d_ws, partials);
  knn_finalize<<<BQ, 256, 0, stream>>>(partials, alphap, betap, (float*)d_out);
}

// Round 3
// 383.524 us; speedup vs baseline: 1.2041x; 1.0369x over previous
//
#include <hip/hip_runtime.h>
#include <hip/hip_bf16.h>

// kNNFit: out[b] = beta * (mean_m F(1 - WHD[m,b]/||W||_1) * Y[m] + alpha)
// WHD[m,b] = s1[b] + sum_d X2[d,m] * (+-W[d]),  sign = (1 - 2*X1[d,b])
// GEMM C[M,64] = X2^T @ (+-W) via mfma_f32_32x32x16_bf16, A-fragments built
// directly in registers (no LDS, no __syncthreads in main): lane (half,col)
// loads rows d = s*16 + half*8 + j at m = m0+col -> exactly its A-frag slots.

#define DD 512
#define MM 131072
#define BQ 64
#define NWG 1024            // 256-thread blocks; each wave owns 32 m's
#define NWAVES (NWG * 4)    // 4096
#define WS_BFRAG 0          // 64 KB: short8[(s*2+t)*64 + lane]
#define WS_META  65536      // float[65]: s1[64], inv_norm
#define WS_PART  131072     // float[64][NWAVES]

typedef __attribute__((ext_vector_type(8))) short short8;        // 8 bf16
typedef __attribute__((ext_vector_type(16))) float floatx16;     // 16 fp32 acc
typedef __attribute__((ext_vector_type(4))) unsigned int uintx4;

__global__ __launch_bounds__(256) void knn_setup(
    const int* __restrict__ X1, const float* __restrict__ W,
    void* __restrict__ ws) {
  short8* bm = (short8*)((char*)ws + WS_BFRAG);
  float* meta = (float*)((char*)ws + WS_META);
  const int tid = threadIdx.x;
  // B fragments: bm[(s*2+t)*64 + lane] holds B[k=s*16+half*8+j][b=t*32+col]
#pragma unroll
  for (int i = 0; i < 16; ++i) {
    const int e = tid + 256 * i;
    const int lane = e & 63, t = (e >> 6) & 1, s = e >> 7;
    const int half = lane >> 5, col = lane & 31;
    const int b = t * 32 + col;
    short8 f;
#pragma unroll
    for (int j = 0; j < 8; ++j) {
      const int d = s * 16 + half * 8 + j;
      unsigned short hb = __builtin_bit_cast(unsigned short, __float2bfloat16(W[d]));
      if (X1[d * BQ + b]) hb ^= 0x8000u;
      f[j] = (short)hb;
    }
    bm[e] = f;
  }
  // s1[b] = sum_d W[d]*X1[d,b], parallel over 4 d-chunks
  __shared__ float s1p[4][64];
  const int chunk = tid >> 6, b = tid & 63;
  float s = 0.f;
  for (int d = chunk * 128; d < chunk * 128 + 128; ++d)
    s += W[d] * (float)X1[d * BQ + b];
  s1p[chunk][b] = s;
  __syncthreads();
  if (tid < 64) {
    meta[tid] = s1p[0][tid] + s1p[1][tid] + s1p[2][tid] + s1p[3][tid];
    float nw = 0.f;
#pragma unroll
    for (int j = 0; j < 8; ++j) nw += fabsf(W[tid * 8 + j]);
    nw += __shfl_xor(nw, 32);
    nw += __shfl_xor(nw, 16);
    nw += __shfl_xor(nw, 8);
    nw += __shfl_xor(nw, 4);
    nw += __shfl_xor(nw, 2);
    nw += __shfl_xor(nw, 1);
    if (tid == 0) meta[64] = 1.0f / (nw + 1e-6f);
  }
}

__global__ __launch_bounds__(256, 4) void knn_main(
    const int* __restrict__ X2, const float* __restrict__ Y,
    const float* __restrict__ kp, const float* __restrict__ jp,
    const void* __restrict__ ws_ro, float* __restrict__ partials) {
  const short8* bm = (const short8*)((const char*)ws_ro + WS_BFRAG);
  const float* meta = (const float*)((const char*)ws_ro + WS_META);

  const int tid = threadIdx.x;
  const int wv = tid >> 6, l = tid & 63;
  const int half = l >> 5, col = l & 31;
  const int m0 = blockIdx.x * 128 + wv * 32;

  floatx16 acc0, acc1;
#pragma unroll
  for (int r = 0; r < 16; ++r) { acc0[r] = 0.f; acc1[r] = 0.f; }

  // lane's 8 loads per step ARE its A-fragment (rows d = s*16 + half*8 + j, m = m0+col)
  const int* g0 = X2 + (size_t)(half * 8) * MM + m0 + col;
  int v[8], vn[8];
#pragma unroll
  for (int j = 0; j < 8; ++j) v[j] = __builtin_nontemporal_load(g0 + (size_t)j * MM);
  short8 bf0 = bm[0 * 64 + l];
  short8 bf1 = bm[1 * 64 + l];

#pragma unroll
  for (int s = 0; s < 32; ++s) {
    short8 nbf0 = bf0, nbf1 = bf1;
    if (s < 31) {  // prefetch next step; no barriers anywhere to drain it
      const int* g = g0 + (size_t)((s + 1) * 16) * MM;
#pragma unroll
      for (int j = 0; j < 8; ++j) vn[j] = __builtin_nontemporal_load(g + (size_t)j * MM);
      nbf0 = bm[((s + 1) * 2 + 0) * 64 + l];
      nbf1 = bm[((s + 1) * 2 + 1) * 64 + l];
    }
    // 0/1 pairs (d, d+1) -> packed bf16 pair: (a | b<<16) * 0x3F80
    uintx4 u;
#pragma unroll
    for (int q = 0; q < 4; ++q)
      u[q] = (unsigned int)(v[2 * q] | (v[2 * q + 1] << 16)) * 0x3F80u;
    const short8 af = __builtin_bit_cast(short8, u);
    acc0 = __builtin_amdgcn_mfma_f32_32x32x16_bf16(af, bf0, acc0, 0, 0, 0);
    acc1 = __builtin_amdgcn_mfma_f32_32x32x16_bf16(af, bf1, acc1, 0, 0, 0);
#pragma unroll
    for (int j = 0; j < 8; ++j) v[j] = vn[j];
    bf0 = nbf0; bf1 = nbf1;
  }

  // epilogue: squash F, weight by Y, reduce over this wave's 32 m's
  const float inv_norm = meta[64];
  const float kk = kp[0], jj = jp[0];
  const float c1 = 1.0f - kk, c2 = 1.0f + jj;
  const float s1b0 = meta[col];
  const float s1b1 = meta[32 + col];
  float p0 = 0.f, p1 = 0.f;
#pragma unroll
  for (int r = 0; r < 16; ++r) {
    const int ml = (r & 3) + 8 * (r >> 2) + 4 * half;  // verified 32x32 C/D row map
    const float ym = Y[m0 + ml];                        // broadcast within half
    {
      const float x = 1.0f - (s1b0 + acc0[r]) * inv_norm;
      const float inner = x * c1 / (kk * (1.0f - 2.0f * fabsf(x)) + 1.0f);
      const float t2 = 2.0f * inner - 1.0f;
      const float fq = 0.5f + 0.5f * t2 * c2 / (-jj * (1.0f - 2.0f * fabsf(t2)) + 1.0f);
      p0 += fq * ym;
    }
    {
      const float x = 1.0f - (s1b1 + acc1[r]) * inv_norm;
      const float inner = x * c1 / (kk * (1.0f - 2.0f * fabsf(x)) + 1.0f);
      const float t2 = 2.0f * inner - 1.0f;
      const float fq = 0.5f + 0.5f * t2 * c2 / (-jj * (1.0f - 2.0f * fabsf(t2)) + 1.0f);
      p1 += fq * ym;
    }
  }
  p0 += __shfl_xor(p0, 32);  // combine the two m-halves
  p1 += __shfl_xor(p1, 32);
  const int gw = blockIdx.x * 4 + wv;
  if (l < 32) {
    partials[(size_t)col * NWAVES + gw] = p0;
    partials[(size_t)(32 + col) * NWAVES + gw] = p1;
  }
}

__global__ __launch_bounds__(256) void knn_finalize(
    const float* __restrict__ partials, const float* __restrict__ alphap,
    const float* __restrict__ betap, float* __restrict__ out) {
  __shared__ float red[256];
  const int b = blockIdx.x, t = threadIdx.x;
  float s = 0.f;
#pragma unroll
  for (int i = 0; i < NWAVES / 256; ++i)
    s += partials[(size_t)b * NWAVES + i * 256 + t];
  red[t] = s;
  __syncthreads();
  if (t < 64) {
    float x = red[t] + red[t + 64] + red[t + 128] + red[t + 192];
    x += __shfl_xor(x, 32);
    x += __shfl_xor(x, 16);
    x += __shfl_xor(x, 8);
    x += __shfl_xor(x, 4);
    x += __shfl_xor(x, 2);
    x += __shfl_xor(x, 1);
    if (t == 0) out[b] = betap[0] * (x * (1.0f / (float)MM) + alphap[0]);
  }
}

extern "C" void kernel_launch(void* const* d_in, const int* in_sizes, int n_in,
                              void* d_out, int out_size, void* d_ws, size_t ws_size,
                              hipStream_t stream) {
  const int* X1 = (const int*)d_in[0];     // [512, 64] int32 bits
  const int* X2 = (const int*)d_in[1];     // [512, 131072] int32 bits
  const float* Y = (const float*)d_in[3];  // [131072]
  const float* W = (const float*)d_in[4];  // [512]
  const float* alphap = (const float*)d_in[5];
  const float* betap = (const float*)d_in[6];
  const float* kp = (const float*)d_in[7];
  const float* jp = (const float*)d_in[8];

  float* partials = (float*)((char*)d_ws + WS_PART);

  knn_setup<<<1, 256, 0, stream>>>(X1, W, d_ws);
  knn_main<<<NWG, 256, 0, stream>>>(X2, Y, kp, jp, d_ws, partials);
  knn_finalize<<<BQ, 256, 0, stream>>>(partials, alphap, betap, (float*)d_out);
}